// Round 3
// baseline (1690.837 us; speedup 1.0000x reference)
//
#include <hip/hip_runtime.h>
#include <hip/hip_bf16.h>

// V=50000, D=512, H=512, L=4, E=40000
#define NV 50000
#define ND 512
#define NH 512
#define NL 4
#define NE 40000
#define TT 60          // targets per block
#define NB 834         // ceil(NV/TT); 834*60 = 50040
#define CAP 128        // per-(block,layer) edge list capacity (mean 48, +11 sigma)
#define MCH 64         // edges per MFMA chunk (M)

typedef short bf16x8 __attribute__((ext_vector_type(8)));  // MFMA A/B frag
typedef float f32x4  __attribute__((ext_vector_type(4)));  // MFMA C/D frag

__device__ __forceinline__ unsigned short f2bf(float f) {
    unsigned int u = __float_as_uint(f);
    u += 0x7FFFu + ((u >> 16) & 1u);
    return (unsigned short)(u >> 16);
}

// ---------------------------------------------------------------------------
// Wt[l][h][k] = bf16(W[l][k][h])   (2 MiB in ws)
// ---------------------------------------------------------------------------
__global__ void wt_kernel(const float* __restrict__ W, unsigned short* __restrict__ Wt) {
    int idx = blockIdx.x * 256 + threadIdx.x;     // NL*ND*NH = 4194304
    int l = idx >> 18;
    int r = idx & 262143;
    int k = r >> 9;
    int h = r & 511;
    Wt[(l << 18) + (h << 9) + k] = f2bf(W[idx]);
}

// ---------------------------------------------------------------------------
// Bucket edges by (target-tile, layer): list entry = src | (local_row << 16)
// ---------------------------------------------------------------------------
__global__ void place_kernel(const int* __restrict__ adj, int* __restrict__ cnt,
                             int* __restrict__ list) {
    int i = blockIdx.x * 256 + threadIdx.x;       // NL*NE = 160000 exact
    int2 p = ((const int2*)adj)[i];               // p.x = src, p.y = tgt
    int l = i / NE;
    int b = p.y / TT;
    int r = p.y % TT;
    int cell = b * NL + l;
    int pos = atomicAdd(&cnt[cell], 1);
    if (pos < CAP) list[cell * CAP + pos] = (p.x & 0xFFFF) | (r << 16);
}

// ---------------------------------------------------------------------------
// Per block: 60 target rows. For each layer l, chunks of 64 edges:
//   gather emb[src] -> bf16 swizzled LDS A-tile (K split in 2 halves of 256),
//   MFMA [64 x K] x Wt[l][h][k], scatter D rows into LDS f32 out-tile via
//   ds_add_f32 (workgroup atomics). Epilogue: ReLU + coalesced store.
// ---------------------------------------------------------------------------
__global__ void __launch_bounds__(256, 1)
edge_gemm(const float* __restrict__ emb,
          const unsigned short* __restrict__ Wt,
          const int* __restrict__ cnt,
          const int* __restrict__ list,
          float* __restrict__ out) {
    __shared__ float  s_out[TT * NH];     // 122880 B, f32 accumulator
    __shared__ bf16x8 s_a[MCH * 32];      // 32768 B: one K-half, 64 rows x 32 slots, slot^(r&7)
    __shared__ int    s_rloc[MCH];

    const int b    = blockIdx.x;
    const int tid  = threadIdx.x;
    const int lane = tid & 63;
    const int wave = tid >> 6;

    // zero out-tile
#pragma unroll
    for (int k = 0; k < (TT * NH / 4) / 256; ++k)   // 30
        ((f32x4*)s_out)[k * 256 + tid] = (f32x4){0.f, 0.f, 0.f, 0.f};
    __syncthreads();

    const int r     = tid >> 2;     // chunk row 0..63 (stage role)
    const int q4    = tid & 3;      // k-quarter within a half (64 f32)
    const int rx    = r & 7;
    const int laneL = lane & 15, laneH = lane >> 4;
    const int c0    = wave * 128;   // this wave's H base
    const int arx   = laneL & 7;

    for (int l = 0; l < NL; ++l) {
        const int cell = b * NL + l;
        int n = cnt[cell]; if (n > CAP) n = CAP;
        const int* lst = list + cell * CAP;
        const bf16x8* wb = (const bf16x8*)(Wt + ((size_t)l << 18));

        for (int c = 0; c * MCH < n; ++c) {
            const int  gr    = c * MCH + r;
            const bool valid = gr < n;
            int src = 0, rloc = 0;
            if (valid) { int e = lst[gr]; src = e & 0xFFFF; rloc = e >> 16; }
            if (q4 == 0) s_rloc[r] = valid ? rloc : 0;   // dummy rows have zero A
            const float* gp = emb + (size_t)src * ND + q4 * 64;

            // ---- stage half 0: load + convert + swizzled write ----
            float4 g[16];
            if (valid) {
#pragma unroll
                for (int j = 0; j < 16; ++j) g[j] = ((const float4*)gp)[j];
            }
#pragma unroll
            for (int j = 0; j < 8; ++j) {
                bf16x8 v = (bf16x8){0,0,0,0,0,0,0,0};
                if (valid) {
                    float4 f0 = g[j*2], f1 = g[j*2+1];
                    v[0]=(short)f2bf(f0.x); v[1]=(short)f2bf(f0.y);
                    v[2]=(short)f2bf(f0.z); v[3]=(short)f2bf(f0.w);
                    v[4]=(short)f2bf(f1.x); v[5]=(short)f2bf(f1.y);
                    v[6]=(short)f2bf(f1.z); v[7]=(short)f2bf(f1.w);
                }
                int s = q4 * 8 + j;
                s_a[r * 32 + (s ^ rx)] = v;
            }
            __syncthreads();

            // ---- issue half-1 gather loads early (hide HBM under MFMA) ----
            float4 g2[16];
            if (valid) {
#pragma unroll
                for (int j = 0; j < 16; ++j) g2[j] = ((const float4*)(gp + 256))[j];
            }

            f32x4 acc[4][8];
#pragma unroll
            for (int mf = 0; mf < 4; ++mf)
#pragma unroll
                for (int nf = 0; nf < 8; ++nf)
                    acc[mf][nf] = (f32x4){0.f, 0.f, 0.f, 0.f};

            // ---- MFMA on K-half 0 ----
#pragma unroll
            for (int kcl = 0; kcl < 8; ++kcl) {
                int slot = kcl * 4 + laneH;
                bf16x8 a[4];
#pragma unroll
                for (int mf = 0; mf < 4; ++mf)
                    a[mf] = s_a[(mf * 16 + laneL) * 32 + (slot ^ arx)];
#pragma unroll
                for (int nf = 0; nf < 8; ++nf) {
                    int h = c0 + nf * 16 + laneL;
                    bf16x8 bb = wb[h * 64 + kcl * 4 + laneH];   // kh=0
#pragma unroll
                    for (int mf = 0; mf < 4; ++mf)
                        acc[mf][nf] = __builtin_amdgcn_mfma_f32_16x16x32_bf16(a[mf], bb, acc[mf][nf], 0, 0, 0);
                }
            }
            __syncthreads();

            // ---- stage half 1 (from prefetched regs) ----
#pragma unroll
            for (int j = 0; j < 8; ++j) {
                bf16x8 v = (bf16x8){0,0,0,0,0,0,0,0};
                if (valid) {
                    float4 f0 = g2[j*2], f1 = g2[j*2+1];
                    v[0]=(short)f2bf(f0.x); v[1]=(short)f2bf(f0.y);
                    v[2]=(short)f2bf(f0.z); v[3]=(short)f2bf(f0.w);
                    v[4]=(short)f2bf(f1.x); v[5]=(short)f2bf(f1.y);
                    v[6]=(short)f2bf(f1.z); v[7]=(short)f2bf(f1.w);
                }
                int s = q4 * 8 + j;
                s_a[r * 32 + (s ^ rx)] = v;
            }
            __syncthreads();

            // ---- MFMA on K-half 1 ----
#pragma unroll
            for (int kcl = 0; kcl < 8; ++kcl) {
                int slot = kcl * 4 + laneH;
                bf16x8 a[4];
#pragma unroll
                for (int mf = 0; mf < 4; ++mf)
                    a[mf] = s_a[(mf * 16 + laneL) * 32 + (slot ^ arx)];
#pragma unroll
                for (int nf = 0; nf < 8; ++nf) {
                    int h = c0 + nf * 16 + laneL;
                    bf16x8 bb = wb[h * 64 + 32 + kcl * 4 + laneH];  // kh=1
#pragma unroll
                    for (int mf = 0; mf < 4; ++mf)
                        acc[mf][nf] = __builtin_amdgcn_mfma_f32_16x16x32_bf16(a[mf], bb, acc[mf][nf], 0, 0, 0);
                }
            }

            // ---- scatter D rows into LDS out-tile (ds_add_f32) ----
            // D layout: col = lane&15 (h), row = (lane>>4)*4 + i
#pragma unroll
            for (int mf = 0; mf < 4; ++mf) {
#pragma unroll
                for (int i = 0; i < 4; ++i) {
                    int er = mf * 16 + laneH * 4 + i;
                    int rl = s_rloc[er];
#pragma unroll
                    for (int nf = 0; nf < 8; ++nf) {
                        int h = c0 + nf * 16 + laneL;
                        atomicAdd(&s_out[rl * NH + h], acc[mf][nf][i]);
                    }
                }
            }
            __syncthreads();   // drain adds; s_a/s_rloc safe for next chunk
        }
    }

    // ---- epilogue: ReLU + coalesced store (each row owned by this block) ----
    const int t0 = b * TT;
#pragma unroll
    for (int k = 0; k < (TT * NH / 4) / 256; ++k) {   // 30
        int idx = k * 256 + tid;           // float4 index over 60*128
        int row = idx >> 7;
        int t   = t0 + row;
        if (t < NV) {
            f32x4 v = ((f32x4*)s_out)[idx];
            v[0] = fmaxf(v[0], 0.f); v[1] = fmaxf(v[1], 0.f);
            v[2] = fmaxf(v[2], 0.f); v[3] = fmaxf(v[3], 0.f);
            ((f32x4*)out)[(size_t)t * 128 + (idx & 127)] = v;
        }
    }
}

extern "C" void kernel_launch(void* const* d_in, const int* in_sizes, int n_in,
                              void* d_out, int out_size, void* d_ws, size_t ws_size,
                              hipStream_t stream) {
    const float* emb = (const float*)d_in[0];   // [V, D] f32
    const int*   adj = (const int*)d_in[1];     // [L, E, 2] i32
    const float* W   = (const float*)d_in[2];   // [L, D, H] f32
    float* out = (float*)d_out;                 // [V, H] f32
    char* ws = (char*)d_ws;

    unsigned short* Wt   = (unsigned short*)ws;               // 2 MiB
    int*            cnt  = (int*)(ws + (2u << 20));           // NB*NL*4 = 13.3 KB
    int*            list = (int*)(ws + (2u << 20) + (1u << 16)); // 1.71 MB

    hipMemsetAsync(cnt, 0, NB * NL * sizeof(int), stream);
    wt_kernel<<<(NL * ND * NH) / 256, 256, 0, stream>>>(W, Wt);
    place_kernel<<<(NL * NE) / 256, 256, 0, stream>>>(adj, cnt, list);
    edge_gemm<<<NB, 256, 0, stream>>>(emb, Wt, cnt, list, out);
}

// Round 4
// 855.849 us; speedup vs baseline: 1.9756x; 1.9756x over previous
//
#include <hip/hip_runtime.h>
#include <hip/hip_bf16.h>

// V=50000, D=512, H=512, L=4, E=40000
#define NV 50000
#define ND 512
#define NH 512
#define NL 4
#define NE 40000
#define TT 64            // targets per block
#define NB 782           // ceil(NV/TT); 782*64 = 50048
#define CAP 128          // per-(block,layer) capacity (mean 51.2, +10.7 sigma)
#define AFW 260          // padded row width of f32 LDS tile (256 + 4)

typedef short bf16x8 __attribute__((ext_vector_type(8)));  // MFMA A/B frag
typedef float f32x4  __attribute__((ext_vector_type(4)));  // MFMA C/D frag

__device__ __forceinline__ unsigned short f2bf(float f) {
    unsigned int u = __float_as_uint(f);
    u += 0x7FFFu + ((u >> 16) & 1u);
    return (unsigned short)(u >> 16);
}

// ---------------------------------------------------------------------------
// Wt[l][h][k] = bf16(W[l][k][h])   (2 MiB in ws)
// ---------------------------------------------------------------------------
__global__ void wt_kernel(const float* __restrict__ W, unsigned short* __restrict__ Wt) {
    int idx = blockIdx.x * 256 + threadIdx.x;     // NL*ND*NH = 4194304
    int l = idx >> 18;
    int r = idx & 262143;
    int k = r >> 9;
    int h = r & 511;
    Wt[(l << 18) + (h << 9) + k] = f2bf(W[idx]);
}

// ---------------------------------------------------------------------------
// Bucket edges by (target-tile, layer): entry = src | (local_t << 16)
// ---------------------------------------------------------------------------
__global__ void place_kernel(const int* __restrict__ adj, int* __restrict__ cnt,
                             int* __restrict__ list) {
    int i = blockIdx.x * 256 + threadIdx.x;       // NL*NE = 160000 exact
    int2 p = ((const int2*)adj)[i];               // p.x = src, p.y = tgt
    int l = i / NE;
    int b = p.y >> 6;                             // tgt / 64
    int lt = p.y & 63;
    int cell = b * NL + l;
    int pos = atomicAdd(&cnt[cell], 1);
    if (pos < CAP) list[cell * CAP + pos] = (p.x & 0xFFFF) | (lt << 16);
}

// ---------------------------------------------------------------------------
// Per block: 64 target rows, acc[4][8] persistent over (l, kh).
// Phases per (l, kh=K-half of 256):
//   Z: zero Af[64][260] f32
//   S: edge-parallel: 16-lane group loads emb[src][kh-half] (4 x float4/lane)
//      and ds_add_f32 into Af[lt][...]
//   C: Af -> bf16 swizzled tile (regs across barrier; aliased into Af)
//   M: MFMA [64 x 256] x Wt[l][:, kh-half], accumulate in regs
// Epilogue: ReLU + direct stores (each out row owned by exactly one block).
// ---------------------------------------------------------------------------
__global__ void __launch_bounds__(256, 2)
agg_gemm(const float* __restrict__ emb,
         const unsigned short* __restrict__ Wt,
         const int* __restrict__ cnt,
         const int* __restrict__ list,
         float* __restrict__ out) {
    __shared__ float Af[TT * AFW];                // 66560 B
    bf16x8* sa = (bf16x8*)Af;                     // aliased bf16 tile: [64 rows][32 slots]

    const int b     = blockIdx.x;
    const int tid   = threadIdx.x;
    const int lane  = tid & 63;
    const int wave  = tid >> 6;
    const int laneL = lane & 15, laneH = lane >> 4;
    const int c0    = wave * 128;                 // wave's H base
    const int arx   = laneL & 7;
    const int grp   = tid >> 4, l16 = tid & 15;   // scatter roles
    const int rc    = tid >> 2, qc = tid & 3;     // convert roles

    f32x4 acc[4][8];
#pragma unroll
    for (int mf = 0; mf < 4; ++mf)
#pragma unroll
        for (int nf = 0; nf < 8; ++nf)
            acc[mf][nf] = (f32x4){0.f, 0.f, 0.f, 0.f};

    for (int l = 0; l < NL; ++l) {
        const int cell = b * NL + l;
        int n = cnt[cell]; if (n > CAP) n = CAP;
        const int* lst = list + cell * CAP;
        const bf16x8* wb = (const bf16x8*)(Wt + ((size_t)l << 18));

#pragma unroll
        for (int kh = 0; kh < 2; ++kh) {
            // ---- Z: zero the f32 tile ----
#pragma unroll
            for (int i = tid; i < TT * AFW / 4; i += 256)
                ((f32x4*)Af)[i] = (f32x4){0.f, 0.f, 0.f, 0.f};
            __syncthreads();

            // ---- S: edge-parallel scatter-aggregate ----
            for (int e = grp; e < n; e += 16) {
                int ent = lst[e];
                int src = ent & 0xFFFF;
                int lt  = ent >> 16;
                const float* gp = emb + (size_t)src * ND + kh * 256;
                float4 f[4];
#pragma unroll
                for (int j = 0; j < 4; ++j)
                    f[j] = *(const float4*)(gp + j * 64 + l16 * 4);
#pragma unroll
                for (int j = 0; j < 4; ++j) {
                    float* ap = &Af[lt * AFW + j * 64 + l16 * 4];
                    atomicAdd(ap + 0, f[j].x);
                    atomicAdd(ap + 1, f[j].y);
                    atomicAdd(ap + 2, f[j].z);
                    atomicAdd(ap + 3, f[j].w);
                }
            }
            __syncthreads();

            // ---- C: convert to bf16 swizzled tile (aliased; regs across bar) ----
            float4 cv[16];
#pragma unroll
            for (int j = 0; j < 16; ++j)
                cv[j] = *(const float4*)&Af[rc * AFW + qc * 64 + j * 4];
            __syncthreads();
#pragma unroll
            for (int j2 = 0; j2 < 8; ++j2) {
                float4 f0 = cv[j2 * 2], f1 = cv[j2 * 2 + 1];
                bf16x8 v;
                v[0]=(short)f2bf(f0.x); v[1]=(short)f2bf(f0.y);
                v[2]=(short)f2bf(f0.z); v[3]=(short)f2bf(f0.w);
                v[4]=(short)f2bf(f1.x); v[5]=(short)f2bf(f1.y);
                v[6]=(short)f2bf(f1.z); v[7]=(short)f2bf(f1.w);
                int slot = qc * 8 + j2;
                sa[rc * 32 + (slot ^ (rc & 7))] = v;
            }
            __syncthreads();

            // ---- M: MFMA K=256, accumulate ----
#pragma unroll
            for (int kc = 0; kc < 8; ++kc) {
                int slot = kc * 4 + laneH;
                bf16x8 a[4];
#pragma unroll
                for (int mf = 0; mf < 4; ++mf)
                    a[mf] = sa[(mf * 16 + laneL) * 32 + (slot ^ arx)];
#pragma unroll
                for (int nf = 0; nf < 8; ++nf) {
                    int h = c0 + nf * 16 + laneL;
                    bf16x8 bb = wb[h * 64 + kh * 32 + kc * 4 + laneH];
#pragma unroll
                    for (int mf = 0; mf < 4; ++mf)
                        acc[mf][nf] = __builtin_amdgcn_mfma_f32_16x16x32_bf16(a[mf], bb, acc[mf][nf], 0, 0, 0);
                }
            }
            __syncthreads();   // M reads done before next Z overwrites
        }
    }

    // ---- Epilogue: ReLU + direct stores ----
    const int t0 = b * TT;
#pragma unroll
    for (int mf = 0; mf < 4; ++mf) {
#pragma unroll
        for (int i = 0; i < 4; ++i) {
            int row = mf * 16 + laneH * 4 + i;
            int t = t0 + row;
            if (t < NV) {
#pragma unroll
                for (int nf = 0; nf < 8; ++nf) {
                    int h = c0 + nf * 16 + laneL;
                    out[(size_t)t * NH + h] = fmaxf(acc[mf][nf][i], 0.f);
                }
            }
        }
    }
}

extern "C" void kernel_launch(void* const* d_in, const int* in_sizes, int n_in,
                              void* d_out, int out_size, void* d_ws, size_t ws_size,
                              hipStream_t stream) {
    const float* emb = (const float*)d_in[0];   // [V, D] f32
    const int*   adj = (const int*)d_in[1];     // [L, E, 2] i32
    const float* W   = (const float*)d_in[2];   // [L, D, H] f32
    float* out = (float*)d_out;                 // [V, H] f32
    char* ws = (char*)d_ws;

    unsigned short* Wt   = (unsigned short*)ws;                  // 2 MiB
    int*            cnt  = (int*)(ws + (2u << 20));              // NB*NL*4 ≈ 12.5 KB
    int*            list = (int*)(ws + (2u << 20) + (1u << 16)); // NB*NL*CAP*4 ≈ 1.6 MB

    hipMemsetAsync(cnt, 0, NB * NL * sizeof(int), stream);
    wt_kernel<<<(NL * ND * NH) / 256, 256, 0, stream>>>(W, Wt);
    place_kernel<<<(NL * NE) / 256, 256, 0, stream>>>(adj, cnt, list);
    agg_gemm<<<NB, 256, 0, stream>>>(emb, Wt, cnt, list, out);
}

// Round 5
// 422.526 us; speedup vs baseline: 4.0017x; 2.0256x over previous
//
#include <hip/hip_runtime.h>
#include <hip/hip_bf16.h>

// V=50000, D=512, H=512, L=4, E=40000
#define NV 50000
#define VP 50048           // 782*64, padded target count
#define ND 512
#define NH 512
#define NL 4
#define NE 40000
#define NB 782             // VP / 64
#define CAP 16             // per-(target,layer) list capacity; deg ~ Poisson(0.8)

typedef short bf16x8 __attribute__((ext_vector_type(8)));  // MFMA A/B frag
typedef float f32x4  __attribute__((ext_vector_type(4)));  // MFMA C/D frag

__device__ __forceinline__ unsigned short f2bf(float f) {
    unsigned int u = __float_as_uint(f);
    u += 0x7FFFu + ((u >> 16) & 1u);
    return (unsigned short)(u >> 16);
}
__device__ __forceinline__ unsigned pack_bf2(float x, float y) {
    return (unsigned)f2bf(x) | ((unsigned)f2bf(y) << 16);
}

// ---------------------------------------------------------------------------
// Wt[l][h][k] = bf16(W[l][k][h])   (2 MiB at ws+0)
// ---------------------------------------------------------------------------
__global__ void wt_kernel(const float* __restrict__ W, unsigned short* __restrict__ Wt) {
    int idx = blockIdx.x * 256 + threadIdx.x;     // NL*ND*NH = 4194304
    int l = idx >> 18;
    int r = idx & 262143;
    int k = r >> 9;
    int h = r & 511;
    Wt[(l << 18) + (h << 9) + k] = f2bf(W[idx]);
}

// ---------------------------------------------------------------------------
// Per-(target,layer) edge lists: cell = tgt*NL + l, entry = src
// ---------------------------------------------------------------------------
__global__ void place_kernel(const int* __restrict__ adj, int* __restrict__ cnt,
                             int* __restrict__ list) {
    int i = blockIdx.x * 256 + threadIdx.x;       // NL*NE = 160000 exact
    int2 p = ((const int2*)adj)[i];               // p.x = src, p.y = tgt
    int l = i / NE;
    int cell = p.y * NL + l;
    int pos = atomicAdd(&cnt[cell], 1);
    if (pos < CAP) list[cell * CAP + pos] = p.x;
}

// ---------------------------------------------------------------------------
// Pass 1: one wave per (t,l) row. agg[l][t][d] (bf16, stored as u32 pairs)
//   = sum over in-edges of emb[src][d], f32 accumulate in regs.
// lsel < 0: wid = t*4+l over VP*NL (grid VP*NL/4 blocks)
// lsel >= 0: wid = t over VP (grid VP/4 blocks), layer fixed, agg is 1 layer.
// ---------------------------------------------------------------------------
__global__ void __launch_bounds__(256)
agg_pull(const float* __restrict__ emb, const int* __restrict__ cnt,
         const int* __restrict__ list, unsigned* __restrict__ agg, int lsel) {
    const int wid  = blockIdx.x * 4 + (threadIdx.x >> 6);
    const int lane = threadIdx.x & 63;
    int t, cell;
    size_t dst;
    if (lsel < 0) {
        t = wid >> 2;
        cell = wid;                                   // t*NL + (wid&3)
        dst = ((size_t)(wid & 3) * VP + t) * 256 + lane;
    } else {
        t = wid;
        cell = t * NL + lsel;
        dst = (size_t)t * 256 + lane;
    }
    int n = cnt[cell]; if (n > CAP) n = CAP;
    const int* lst = list + cell * CAP;

    float2 s0 = {0.f,0.f}, s1 = {0.f,0.f}, s2 = {0.f,0.f}, s3 = {0.f,0.f};
    int j = 0;
    for (; j + 2 <= n; j += 2) {
        const float2* p0 = (const float2*)(emb + (size_t)lst[j]     * ND) + lane;
        const float2* p1 = (const float2*)(emb + (size_t)lst[j + 1] * ND) + lane;
        float2 a0 = p0[0], a1 = p0[64], a2 = p0[128], a3 = p0[192];
        float2 b0 = p1[0], b1 = p1[64], b2 = p1[128], b3 = p1[192];
        s0.x += a0.x + b0.x; s0.y += a0.y + b0.y;
        s1.x += a1.x + b1.x; s1.y += a1.y + b1.y;
        s2.x += a2.x + b2.x; s2.y += a2.y + b2.y;
        s3.x += a3.x + b3.x; s3.y += a3.y + b3.y;
    }
    if (j < n) {
        const float2* p0 = (const float2*)(emb + (size_t)lst[j] * ND) + lane;
        float2 a0 = p0[0], a1 = p0[64], a2 = p0[128], a3 = p0[192];
        s0.x += a0.x; s0.y += a0.y;  s1.x += a1.x; s1.y += a1.y;
        s2.x += a2.x; s2.y += a2.y;  s3.x += a3.x; s3.y += a3.y;
    }
    agg[dst]       = pack_bf2(s0.x, s0.y);
    agg[dst + 64]  = pack_bf2(s1.x, s1.y);
    agg[dst + 128] = pack_bf2(s2.x, s2.y);
    agg[dst + 192] = pack_bf2(s3.x, s3.y);
}

// ---------------------------------------------------------------------------
// Pass 2: out[t0..t0+64] = (relu of) [sum over NLY layers] agg[ll]·W[ll]
// Per (ll,kh) phase: reg-staged A prefetch -> LDS (swizzled) -> MFMA.
// acc[4][8] persistent; B streamed from L2-resident Wt.
// ---------------------------------------------------------------------------
template<int NLY, int FIRST, int LAST>
__global__ void __launch_bounds__(256, 2)
gemm_k(const unsigned short* __restrict__ agg,
       const unsigned short* __restrict__ Wt,
       float* __restrict__ out) {
    __shared__ bf16x8 s_a[64 * 32];   // 32 KiB: [row][slot ^ (row&7)]

    const int b = blockIdx.x, t0 = b * 64;
    const int tid = threadIdx.x, lane = tid & 63, wave = tid >> 6;
    const int laneL = lane & 15, laneH = lane >> 4;
    const int c0 = wave * 128, arx = laneL & 7;
    const int r = tid >> 2, q = tid & 3, rx = r & 7;

    f32x4 acc[4][8];
#pragma unroll
    for (int mf = 0; mf < 4; ++mf)
#pragma unroll
        for (int nf = 0; nf < 8; ++nf)
            acc[mf][nf] = (f32x4){0.f, 0.f, 0.f, 0.f};

    const bf16x8* ab = (const bf16x8*)agg;
    const bf16x8* wbb = (const bf16x8*)Wt;

    // prologue: stage phase-0 A into regs (row r, quarter q)
    bf16x8 stg[8];
    {
        const bf16x8* ap = ab + ((size_t)(t0 + r)) * 64 + q * 8;
#pragma unroll
        for (int jj = 0; jj < 8; ++jj) stg[jj] = ap[jj];
    }

    for (int p = 0; p < NLY * 2; ++p) {
        const int ll = p >> 1, kh = p & 1;
        // write staged regs to LDS (swizzled)
#pragma unroll
        for (int jj = 0; jj < 8; ++jj)
            s_a[r * 32 + ((q * 8 + jj) ^ rx)] = stg[jj];
        __syncthreads();

        // prefetch next phase's A into regs (overlaps MFMA below)
        if (p + 1 < NLY * 2) {
            const int np = p + 1, nl = np >> 1, nk = np & 1;
            const bf16x8* ap = ab + ((size_t)nl * VP + t0 + r) * 64 + nk * 32 + q * 8;
#pragma unroll
            for (int jj = 0; jj < 8; ++jj) stg[jj] = ap[jj];
        }

        const bf16x8* wb = wbb + ((size_t)ll << 15);   // 512*512/8 per layer
#pragma unroll
        for (int kc = 0; kc < 8; ++kc) {
            const int slot = kc * 4 + laneH;
            bf16x8 a[4];
#pragma unroll
            for (int mf = 0; mf < 4; ++mf)
                a[mf] = s_a[(mf * 16 + laneL) * 32 + (slot ^ arx)];
#pragma unroll
            for (int nf = 0; nf < 8; ++nf) {
                bf16x8 bb = wb[(size_t)(c0 + nf * 16 + laneL) * 64 + kh * 32 + slot];
#pragma unroll
                for (int mf = 0; mf < 4; ++mf)
                    acc[mf][nf] = __builtin_amdgcn_mfma_f32_16x16x32_bf16(a[mf], bb, acc[mf][nf], 0, 0, 0);
            }
        }
        __syncthreads();   // MFMA reads done before next phase overwrites s_a
    }

    // epilogue: D layout col=lane&15, row=(lane>>4)*4+i
#pragma unroll
    for (int mf = 0; mf < 4; ++mf) {
#pragma unroll
        for (int i = 0; i < 4; ++i) {
            int row = mf * 16 + laneH * 4 + i;
            int t = t0 + row;
            if (t < NV) {
#pragma unroll
                for (int nf = 0; nf < 8; ++nf) {
                    int h = c0 + nf * 16 + laneL;
                    size_t o = (size_t)t * NH + h;
                    float v = acc[mf][nf][i];
                    if (!FIRST) v += out[o];
                    if (LAST) v = fmaxf(v, 0.f);
                    out[o] = v;
                }
            }
        }
    }
}

// ---------------------------------------------------------------------------
// Legacy fallback (R1 pipeline): scatter-form with global atomics. Only used
// if ws_size is too small for the agg paths.
// ---------------------------------------------------------------------------
__global__ void __launch_bounds__(256)
legacy_msg(const float* __restrict__ emb, const int* __restrict__ adj,
           const unsigned short* __restrict__ Wt, float* __restrict__ out) {
    __shared__ bf16x8 s_a[32 * 64];
    __shared__ int s_src[32];
    __shared__ int s_tgt[32];
    const int bx = blockIdx.x;
    const int l = bx / (NE / 32);
    const int ebase = (bx % (NE / 32)) * 32;
    const int tid = threadIdx.x, lane = tid & 63, wave = tid >> 6;
    if (tid < 32) {
        int2 p = *(const int2*)(adj + ((size_t)l * NE + ebase + tid) * 2);
        s_src[tid] = p.x; s_tgt[tid] = p.y;
    }
    __syncthreads();
    {
        const int r = tid >> 3, part = tid & 7, k0 = part * 64, rxx = r & 7;
        const float* g = emb + (size_t)s_src[r] * ND + k0;
#pragma unroll
        for (int j = 0; j < 8; ++j) {
            float4 f0 = *(const float4*)(g + j * 8);
            float4 f1 = *(const float4*)(g + j * 8 + 4);
            bf16x8 v;
            v[0]=(short)f2bf(f0.x); v[1]=(short)f2bf(f0.y);
            v[2]=(short)f2bf(f0.z); v[3]=(short)f2bf(f0.w);
            v[4]=(short)f2bf(f1.x); v[5]=(short)f2bf(f1.y);
            v[6]=(short)f2bf(f1.z); v[7]=(short)f2bf(f1.w);
            int slot = (k0 >> 3) + j;
            s_a[r * 64 + (slot ^ rxx)] = v;
        }
    }
    __syncthreads();
    const int c0 = wave * 128, laneL = lane & 15, laneH = lane >> 4, arx = laneL & 7;
    f32x4 acc[2][8];
#pragma unroll
    for (int mf = 0; mf < 2; ++mf)
#pragma unroll
        for (int nf = 0; nf < 8; ++nf) acc[mf][nf] = (f32x4){0.f,0.f,0.f,0.f};
    const bf16x8* wb = (const bf16x8*)(Wt + ((size_t)l << 18));
#pragma unroll
    for (int kc = 0; kc < 16; ++kc) {
        int slot = kc * 4 + laneH;
        bf16x8 a0 = s_a[laneL * 64 + (slot ^ arx)];
        bf16x8 a1 = s_a[(16 + laneL) * 64 + (slot ^ arx)];
#pragma unroll
        for (int nf = 0; nf < 8; ++nf) {
            bf16x8 b = wb[(c0 + nf * 16 + laneL) * 64 + slot];
            acc[0][nf] = __builtin_amdgcn_mfma_f32_16x16x32_bf16(a0, b, acc[0][nf], 0, 0, 0);
            acc[1][nf] = __builtin_amdgcn_mfma_f32_16x16x32_bf16(a1, b, acc[1][nf], 0, 0, 0);
        }
    }
#pragma unroll
    for (int mf = 0; mf < 2; ++mf)
#pragma unroll
        for (int nf = 0; nf < 8; ++nf) {
            int h = c0 + nf * 16 + laneL;
#pragma unroll
            for (int i = 0; i < 4; ++i) {
                int er = mf * 16 + laneH * 4 + i;
                atomicAdd(out + (size_t)s_tgt[er] * NH + h, acc[mf][nf][i]);
            }
        }
}
__global__ void legacy_relu(float* __restrict__ o, int n4) {
    int stride = gridDim.x * blockDim.x;
    for (int i = blockIdx.x * blockDim.x + threadIdx.x; i < n4; i += stride) {
        float4 v = ((float4*)o)[i];
        v.x = fmaxf(v.x, 0.f); v.y = fmaxf(v.y, 0.f);
        v.z = fmaxf(v.z, 0.f); v.w = fmaxf(v.w, 0.f);
        ((float4*)o)[i] = v;
    }
}

extern "C" void kernel_launch(void* const* d_in, const int* in_sizes, int n_in,
                              void* d_out, int out_size, void* d_ws, size_t ws_size,
                              hipStream_t stream) {
    const float* emb = (const float*)d_in[0];   // [V, D] f32
    const int*   adj = (const int*)d_in[1];     // [L, E, 2] i32
    const float* W   = (const float*)d_in[2];   // [L, D, H] f32
    float* out = (float*)d_out;                 // [V, H] f32
    char* ws = (char*)d_ws;

    unsigned short* Wt = (unsigned short*)ws;                  // @0,   4 MiB reserved
    int* cnt  = (int*)(ws + (4u << 20));                       // @4M,  800,768 B
    int* list = (int*)(ws + (5u << 20));                       // @5M,  12,812,288 B
    unsigned short* agg = (unsigned short*)(ws + (19u << 20)); // @19M

    const size_t agg_full  = (size_t)NL * VP * ND * 2;         // 204,996,608
    const size_t agg_one   = (size_t)VP * ND * 2;              //  51,249,152
    const size_t need_full = (19u << 20) + agg_full;           // ~225 MB
    const size_t need_one  = (19u << 20) + agg_one;            // ~71 MB

    wt_kernel<<<(NL * ND * NH) / 256, 256, 0, stream>>>(W, Wt);

    if (ws_size >= need_one) {
        hipMemsetAsync(cnt, 0, (size_t)VP * NL * sizeof(int), stream);
        place_kernel<<<(NL * NE) / 256, 256, 0, stream>>>(adj, cnt, list);
        if (ws_size >= need_full) {
            agg_pull<<<(VP * NL) / 4, 256, 0, stream>>>(emb, cnt, list, (unsigned*)agg, -1);
            gemm_k<4, 1, 1><<<NB, 256, 0, stream>>>(agg, Wt, out);
        } else {
            // layer-at-a-time: accumulate into out, relu on last
            agg_pull<<<VP / 4, 256, 0, stream>>>(emb, cnt, list, (unsigned*)agg, 0);
            gemm_k<1, 1, 0><<<NB, 256, 0, stream>>>(agg, Wt, out);
            agg_pull<<<VP / 4, 256, 0, stream>>>(emb, cnt, list, (unsigned*)agg, 1);
            gemm_k<1, 0, 0><<<NB, 256, 0, stream>>>(agg, Wt + (1u << 18), out);
            agg_pull<<<VP / 4, 256, 0, stream>>>(emb, cnt, list, (unsigned*)agg, 2);
            gemm_k<1, 0, 0><<<NB, 256, 0, stream>>>(agg, Wt + (2u << 18), out);
            agg_pull<<<VP / 4, 256, 0, stream>>>(emb, cnt, list, (unsigned*)agg, 3);
            gemm_k<1, 0, 1><<<NB, 256, 0, stream>>>(agg, Wt + (3u << 18), out);
        }
    } else {
        // legacy scatter path (R1)
        hipMemsetAsync(d_out, 0, (size_t)out_size * sizeof(float), stream);
        legacy_msg<<<NL * (NE / 32), 256, 0, stream>>>(emb, adj, Wt, out);
        legacy_relu<<<2048, 256, 0, stream>>>(out, out_size / 4);
    }
}

// Round 6
// 323.473 us; speedup vs baseline: 5.2271x; 1.3062x over previous
//
#include <hip/hip_runtime.h>
#include <hip/hip_bf16.h>

// V=50000, D=512, H=512, L=4, E=40000
#define NV 50000
#define VP 50048           // 391*128, padded target count
#define ND 512
#define NH 512
#define NL 4
#define NE 40000
#define NB 391             // VP / 128  (M-tiles of gemm_all)
#define CAP 16             // per-(target,layer) list capacity; deg ~ Poisson(0.8)
#define KTOT 2048          // NL*ND concatenated K

typedef short bf16x8 __attribute__((ext_vector_type(8)));  // MFMA A/B frag
typedef float f32x4  __attribute__((ext_vector_type(4)));  // MFMA C/D frag

__device__ __forceinline__ unsigned short f2bf(float f) {
    unsigned int u = __float_as_uint(f);
    u += 0x7FFFu + ((u >> 16) & 1u);
    return (unsigned short)(u >> 16);
}
__device__ __forceinline__ unsigned pack_bf2(float x, float y) {
    return (unsigned)f2bf(x) | ((unsigned)f2bf(y) << 16);
}

// async global->LDS, 16B per lane; LDS dest is wave-uniform base + lane*16
#define GLL16(gp, lp) __builtin_amdgcn_global_load_lds( \
    (const __attribute__((address_space(1))) void*)(gp), \
    (__attribute__((address_space(3))) void*)(lp), 16, 0, 0)

// ---------------------------------------------------------------------------
// Wt2[h][l*512+k] = bf16(W[l][k][h])   (2 MiB at ws+0) — B^T, K-concat layout
// ---------------------------------------------------------------------------
__global__ void wt2_kernel(const float* __restrict__ W, unsigned short* __restrict__ Wt2) {
    int idx = blockIdx.x * 256 + threadIdx.x;     // NL*ND*NH = 4194304
    int l = idx >> 18;
    int r = idx & 262143;
    int k = r >> 9;
    int h = r & 511;
    Wt2[((size_t)h << 11) + (l << 9) + k] = f2bf(W[idx]);
}

// ---------------------------------------------------------------------------
// Per-(target,layer) edge lists: cell = tgt*NL + l, entry = src
// ---------------------------------------------------------------------------
__global__ void place_kernel(const int* __restrict__ adj, int* __restrict__ cnt,
                             int* __restrict__ list) {
    int i = blockIdx.x * 256 + threadIdx.x;       // NL*NE = 160000 exact
    int2 p = ((const int2*)adj)[i];               // p.x = src, p.y = tgt
    int l = i / NE;
    int cell = p.y * NL + l;
    int pos = atomicAdd(&cnt[cell], 1);
    if (pos < CAP) list[cell * CAP + pos] = p.x;
}

// ---------------------------------------------------------------------------
// Pass 1: one wave per (t,l). agg2[t][l*512 + d] (bf16 as u32 pairs)
//   = sum over in-edges of emb[src][d], f32 accumulate in regs.
// ---------------------------------------------------------------------------
__global__ void __launch_bounds__(256)
agg_pull(const float* __restrict__ emb, const int* __restrict__ cnt,
         const int* __restrict__ list, unsigned* __restrict__ agg2) {
    const int wid  = blockIdx.x * 4 + (threadIdx.x >> 6);   // over VP*NL
    const int lane = threadIdx.x & 63;
    const int t    = wid >> 2;
    const int l    = wid & 3;
    const int cell = wid;                                    // t*NL + l
    const size_t dst = (size_t)t * 1024 + l * 256 + lane;    // u32 units

    int n = cnt[cell]; if (n > CAP) n = CAP;
    const int* lst = list + cell * CAP;

    float2 s0 = {0.f,0.f}, s1 = {0.f,0.f}, s2 = {0.f,0.f}, s3 = {0.f,0.f};
    int j = 0;
    for (; j + 2 <= n; j += 2) {
        const float2* p0 = (const float2*)(emb + (size_t)lst[j]     * ND) + lane;
        const float2* p1 = (const float2*)(emb + (size_t)lst[j + 1] * ND) + lane;
        float2 a0 = p0[0], a1 = p0[64], a2 = p0[128], a3 = p0[192];
        float2 b0 = p1[0], b1 = p1[64], b2 = p1[128], b3 = p1[192];
        s0.x += a0.x + b0.x; s0.y += a0.y + b0.y;
        s1.x += a1.x + b1.x; s1.y += a1.y + b1.y;
        s2.x += a2.x + b2.x; s2.y += a2.y + b2.y;
        s3.x += a3.x + b3.x; s3.y += a3.y + b3.y;
    }
    if (j < n) {
        const float2* p0 = (const float2*)(emb + (size_t)lst[j] * ND) + lane;
        float2 a0 = p0[0], a1 = p0[64], a2 = p0[128], a3 = p0[192];
        s0.x += a0.x; s0.y += a0.y;  s1.x += a1.x; s1.y += a1.y;
        s2.x += a2.x; s2.y += a2.y;  s3.x += a3.x; s3.y += a3.y;
    }
    agg2[dst]       = pack_bf2(s0.x, s0.y);
    agg2[dst + 64]  = pack_bf2(s1.x, s1.y);
    agg2[dst + 128] = pack_bf2(s2.x, s2.y);
    agg2[dst + 192] = pack_bf2(s3.x, s3.y);
}

// ---------------------------------------------------------------------------
// Pass 2: out = relu(agg2[VP][2048] x Wt2[512][2048]^T), M-tile 128, N=512.
// m97-style: global_load_lds staging (pre-swizzled source), swizzled ds_read,
// 2-barrier K-loop, 8 waves (2M x 4N), acc[4][8] per wave.
// ---------------------------------------------------------------------------
__global__ void __launch_bounds__(512, 2)
gemm_all(const unsigned short* __restrict__ agg2,
         const unsigned short* __restrict__ Wt2,
         float* __restrict__ out) {
    __shared__ unsigned short s_a[128 * 64];   // 16 KiB, [row][slot^(row&7)] of 16B slots
    __shared__ unsigned short s_b[512 * 64];   // 64 KiB, same swizzle

    const int tid   = threadIdx.x;             // 0..511
    const int lane  = tid & 63;
    const int wave  = tid >> 6;                // 0..7
    const int wm    = wave >> 2;               // M half (0..1)
    const int wn    = wave & 3;                // N quarter (0..3)
    const int laneL = lane & 15, laneH = lane >> 4;
    const int t0    = blockIdx.x * 128;

    // staging geometry: round covers LDS rows [r*64 + wave*8 + lane/8], slot lane&7
    const int srow  = wave * 8 + (lane >> 3);
    const int sslot = lane & 7;
    const unsigned short* aptr[2];
    const unsigned short* bptr[8];
#pragma unroll
    for (int r2 = 0; r2 < 2; ++r2) {
        int row = r2 * 64 + srow;
        aptr[r2] = agg2 + (size_t)(t0 + row) * KTOT + (sslot ^ (row & 7)) * 8;
    }
#pragma unroll
    for (int r8 = 0; r8 < 8; ++r8) {
        int row = r8 * 64 + srow;
        bptr[r8] = Wt2 + (size_t)row * KTOT + (sslot ^ (row & 7)) * 8;
    }
    unsigned short* alds = s_a + wave * 512;   // wave-uniform base (1 KiB/wave/round)
    unsigned short* blds = s_b + wave * 512;

    f32x4 acc[4][8];
#pragma unroll
    for (int mi = 0; mi < 4; ++mi)
#pragma unroll
        for (int ni = 0; ni < 8; ++ni)
            acc[mi][ni] = (f32x4){0.f, 0.f, 0.f, 0.f};

    for (int kt = 0; kt < KTOT / 64; ++kt) {
        const int ko = kt * 64;
        // ---- stage tile kt (async, linear LDS dest, pre-swizzled global src) ----
#pragma unroll
        for (int r2 = 0; r2 < 2; ++r2)
            GLL16(aptr[r2] + ko, alds + r2 * 4096);
#pragma unroll
        for (int r8 = 0; r8 < 8; ++r8)
            GLL16(bptr[r8] + ko, blds + r8 * 4096);
        __syncthreads();   // compiler drains vmcnt before barrier

        // ---- compute: 2 k-chunks of 32, 64 MFMA / wave ----
#pragma unroll
        for (int kk2 = 0; kk2 < 2; ++kk2) {
            bf16x8 a[4], b[8];
#pragma unroll
            for (int mi = 0; mi < 4; ++mi) {
                int row = wm * 64 + mi * 16 + laneL;
                int slot = kk2 * 4 + laneH;
                a[mi] = *(const bf16x8*)(s_a + row * 64 + ((slot ^ (row & 7)) << 3));
            }
#pragma unroll
            for (int ni = 0; ni < 8; ++ni) {
                int row = wn * 128 + ni * 16 + laneL;
                int slot = kk2 * 4 + laneH;
                b[ni] = *(const bf16x8*)(s_b + row * 64 + ((slot ^ (row & 7)) << 3));
            }
#pragma unroll
            for (int ni = 0; ni < 8; ++ni)
#pragma unroll
                for (int mi = 0; mi < 4; ++mi)
                    acc[mi][ni] = __builtin_amdgcn_mfma_f32_16x16x32_bf16(a[mi], b[ni], acc[mi][ni], 0, 0, 0);
        }
        __syncthreads();   // LDS reads done before next stage overwrites
    }

    // ---- epilogue: ReLU + direct stores (D: col=lane&15, row=(lane>>4)*4+i) ----
#pragma unroll
    for (int mi = 0; mi < 4; ++mi) {
#pragma unroll
        for (int i = 0; i < 4; ++i) {
            int row = wm * 64 + mi * 16 + laneH * 4 + i;
            int t = t0 + row;
            if (t < NV) {
#pragma unroll
                for (int ni = 0; ni < 8; ++ni) {
                    int h = wn * 128 + ni * 16 + laneL;
                    out[(size_t)t * NH + h] = fmaxf(acc[mi][ni][i], 0.f);
                }
            }
        }
    }
}

// ---------------------------------------------------------------------------
// Legacy fallback (R1 pipeline) if workspace is too small for agg2.
// ---------------------------------------------------------------------------
__global__ void wt_legacy(const float* __restrict__ W, unsigned short* __restrict__ Wt) {
    int idx = blockIdx.x * 256 + threadIdx.x;
    int l = idx >> 18;
    int r = idx & 262143;
    int k = r >> 9;
    int h = r & 511;
    Wt[(l << 18) + (h << 9) + k] = f2bf(W[idx]);
}
__global__ void __launch_bounds__(256)
legacy_msg(const float* __restrict__ emb, const int* __restrict__ adj,
           const unsigned short* __restrict__ Wt, float* __restrict__ out) {
    __shared__ bf16x8 s_a[32 * 64];
    __shared__ int s_src[32];
    __shared__ int s_tgt[32];
    const int bx = blockIdx.x;
    const int l = bx / (NE / 32);
    const int ebase = (bx % (NE / 32)) * 32;
    const int tid = threadIdx.x, lane = tid & 63, wave = tid >> 6;
    if (tid < 32) {
        int2 p = *(const int2*)(adj + ((size_t)l * NE + ebase + tid) * 2);
        s_src[tid] = p.x; s_tgt[tid] = p.y;
    }
    __syncthreads();
    {
        const int r = tid >> 3, part = tid & 7, k0 = part * 64, rxx = r & 7;
        const float* g = emb + (size_t)s_src[r] * ND + k0;
#pragma unroll
        for (int j = 0; j < 8; ++j) {
            float4 f0 = *(const float4*)(g + j * 8);
            float4 f1 = *(const float4*)(g + j * 8 + 4);
            bf16x8 v;
            v[0]=(short)f2bf(f0.x); v[1]=(short)f2bf(f0.y);
            v[2]=(short)f2bf(f0.z); v[3]=(short)f2bf(f0.w);
            v[4]=(short)f2bf(f1.x); v[5]=(short)f2bf(f1.y);
            v[6]=(short)f2bf(f1.z); v[7]=(short)f2bf(f1.w);
            int slot = (k0 >> 3) + j;
            s_a[r * 64 + (slot ^ rxx)] = v;
        }
    }
    __syncthreads();
    const int c0 = wave * 128, laneL = lane & 15, laneH = lane >> 4, arx = laneL & 7;
    f32x4 acc[2][8];
#pragma unroll
    for (int mf = 0; mf < 2; ++mf)
#pragma unroll
        for (int nf = 0; nf < 8; ++nf) acc[mf][nf] = (f32x4){0.f,0.f,0.f,0.f};
    const bf16x8* wb = (const bf16x8*)(Wt + ((size_t)l << 18));
#pragma unroll
    for (int kc = 0; kc < 16; ++kc) {
        int slot = kc * 4 + laneH;
        bf16x8 a0 = s_a[laneL * 64 + (slot ^ arx)];
        bf16x8 a1 = s_a[(16 + laneL) * 64 + (slot ^ arx)];
#pragma unroll
        for (int nf = 0; nf < 8; ++nf) {
            bf16x8 b = wb[(c0 + nf * 16 + laneL) * 64 + slot];
            acc[0][nf] = __builtin_amdgcn_mfma_f32_16x16x32_bf16(a0, b, acc[0][nf], 0, 0, 0);
            acc[1][nf] = __builtin_amdgcn_mfma_f32_16x16x32_bf16(a1, b, acc[1][nf], 0, 0, 0);
        }
    }
#pragma unroll
    for (int mf = 0; mf < 2; ++mf)
#pragma unroll
        for (int nf = 0; nf < 8; ++nf) {
            int h = c0 + nf * 16 + laneL;
#pragma unroll
            for (int i = 0; i < 4; ++i) {
                int er = mf * 16 + laneH * 4 + i;
                atomicAdd(out + (size_t)s_tgt[er] * NH + h, acc[mf][nf][i]);
            }
        }
}
__global__ void legacy_relu(float* __restrict__ o, int n4) {
    int stride = gridDim.x * blockDim.x;
    for (int i = blockIdx.x * blockDim.x + threadIdx.x; i < n4; i += stride) {
        float4 v = ((float4*)o)[i];
        v.x = fmaxf(v.x, 0.f); v.y = fmaxf(v.y, 0.f);
        v.z = fmaxf(v.z, 0.f); v.w = fmaxf(v.w, 0.f);
        ((float4*)o)[i] = v;
    }
}

extern "C" void kernel_launch(void* const* d_in, const int* in_sizes, int n_in,
                              void* d_out, int out_size, void* d_ws, size_t ws_size,
                              hipStream_t stream) {
    const float* emb = (const float*)d_in[0];   // [V, D] f32
    const int*   adj = (const int*)d_in[1];     // [L, E, 2] i32
    const float* W   = (const float*)d_in[2];   // [L, D, H] f32
    float* out = (float*)d_out;                 // [V, H] f32
    char* ws = (char*)d_ws;

    unsigned short* Wt2  = (unsigned short*)ws;                 // @0,   2 MiB (4 reserved)
    int*            cnt  = (int*)(ws + (4u << 20));             // @4M,  800,768 B
    int*            list = (int*)(ws + (5u << 20));             // @5M,  12.8 MB
    unsigned short* agg2 = (unsigned short*)(ws + (19u << 20)); // @19M, 205 MB

    const size_t need = (19u << 20) + (size_t)VP * KTOT * 2;    // ~224 MB

    if (ws_size >= need) {
        hipMemsetAsync(cnt, 0, (size_t)VP * NL * sizeof(int), stream);
        wt2_kernel<<<(NL * ND * NH) / 256, 256, 0, stream>>>(W, Wt2);
        place_kernel<<<(NL * NE) / 256, 256, 0, stream>>>(adj, cnt, list);
        agg_pull<<<(VP * NL) / 4, 256, 0, stream>>>(emb, cnt, list, (unsigned*)agg2);
        gemm_all<<<NB, 512, 0, stream>>>(agg2, Wt2, out);
    } else {
        // legacy scatter path (R1)
        hipMemsetAsync(d_out, 0, (size_t)out_size * sizeof(float), stream);
        wt_legacy<<<(NL * ND * NH) / 256, 256, 0, stream>>>(W, Wt2);
        legacy_msg<<<NL * (NE / 32), 256, 0, stream>>>(emb, adj, Wt2, out);
        legacy_relu<<<2048, 256, 0, stream>>>(out, out_size / 4);
    }
}